// Round 1
// baseline (4954.450 us; speedup 1.0000x reference)
//
#include <hip/hip_runtime.h>
#include <math.h>

#define T_STEPS 8
#define BATCH 4
#define G 32
#define HW 4096
#define W64 64
#define COUT 65
#define CHUNK 8

// ---------------------------------------------------------------------------
// Generic tiled 3x3 conv kernel.
// MODE 0: "conv_x" precompute — out = conv(input_x_part) + bias, written raw
//          to convx buffer for all (dir, t, b).
// MODE 1: recurrent step — acc = convx[dir][t] + conv(c_buf); A = tanh(acc);
//          co<32  -> write A to out tensor (h), and lr_h at last fwd step
//          co>=32 -> write A to A_buf (cand channels + gate channel)
// Block: 256 threads = 4 waves. Each wave owns 4 consecutive couts
// (co = co_grp*16 + wave*4 + j), lanes cover a ROWSx64 pixel tile in strips.
// ---------------------------------------------------------------------------
template<int ROWS, int MODE>
__global__ __launch_bounds__(256) void conv_kernel(
    const float* __restrict__ in_base, int in_ctot, int cin,
    const float* __restrict__ w_f, const float* __restrict__ w_b,
    const float* __restrict__ b_f, const float* __restrict__ b_b,
    int ci_total, int w_cin_off,
    float* __restrict__ convx,
    float* __restrict__ out_t, float* __restrict__ A_buf,
    float* __restrict__ lr_h,
    int layer, int step)
{
    __shared__ float lds_in[CHUNK * (ROWS + 2) * 66];
    __shared__ float lds_w[16 * CHUNK * 9];

    const int tid  = threadIdx.x;
    const int lane = tid & 63;
    const int wv   = tid >> 6;           // wave id 0..3 = cout subgroup

    int dir, t, b;
    if (MODE == 0) {
        int z = blockIdx.z;              // dir*T*B
        dir = z >> 5; t = (z >> 2) & 7; b = z & 3;
    } else {
        int z = blockIdx.z;              // dir*B
        dir = z >> 2; b = z & 3;
        t = dir ? (T_STEPS - 1 - step) : step;
    }
    const int co_grp = blockIdx.y;       // 5 groups of 16 couts (65 valid)
    const int row0   = blockIdx.x * ROWS;

    constexpr int P = (ROWS == 8) ? 8 : 4;   // pixels per thread strip
    int row, col0;
    if (ROWS == 8) { row = lane >> 3; col0 = (lane & 7) * 8; }
    else           { row = lane >> 4; col0 = (lane & 15) * 4; }

    const float* wsel = dir ? w_b : w_f;
    const float* bsel = dir ? b_b : b_f;

    size_t in_chan0;
    if (MODE == 0) in_chan0 = (size_t)(t * BATCH + b) * in_ctot;
    else           in_chan0 = (size_t)(dir * BATCH + b) * 32;

    const size_t img65 = ((size_t)(dir * T_STEPS + t) * BATCH + b) * COUT;
    const int px0 = (row0 + row) * W64 + col0;

    float acc[4][P];
    #pragma unroll
    for (int j = 0; j < 4; ++j) {
        int co = co_grp * 16 + wv * 4 + j;
        if (MODE == 0) {
            float init = (co < COUT) ? bsel[co] : 0.f;
            #pragma unroll
            for (int p = 0; p < P; ++p) acc[j][p] = init;
        } else {
            if (co < COUT) {
                const float* src = convx + (img65 + co) * HW + px0;
                #pragma unroll
                for (int p = 0; p < P; ++p) acc[j][p] = src[p];
            } else {
                #pragma unroll
                for (int p = 0; p < P; ++p) acc[j][p] = 0.f;
            }
        }
    }

    const int n_chunks = (cin + CHUNK - 1) / CHUNK;
    for (int ch = 0; ch < n_chunks; ++ch) {
        const int cin_base = ch * CHUNK;
        __syncthreads();
        // stage input tile: CHUNK channels x (ROWS+2) rows x 66 cols (halo, 0-pad)
        for (int i = tid; i < CHUNK * (ROWS + 2) * 66; i += 256) {
            int cc  = i / ((ROWS + 2) * 66);
            int rem = i - cc * ((ROWS + 2) * 66);
            int r   = rem / 66;
            int colp = rem - r * 66;
            int gr = row0 + r - 1;
            int gc = colp - 1;
            int c  = cin_base + cc;
            float v = 0.f;
            if (c < cin && (unsigned)gr < 64u && (unsigned)gc < 64u)
                v = in_base[(in_chan0 + c) * HW + gr * W64 + gc];
            lds_in[i] = v;
        }
        // stage weights: 16 couts x CHUNK cin x 9 taps
        for (int i = tid; i < 16 * CHUNK * 9; i += 256) {
            int col_ = i / (CHUNK * 9);
            int rem  = i - col_ * (CHUNK * 9);
            int cc   = rem / 9;
            int tap  = rem - cc * 9;
            int co   = co_grp * 16 + col_;
            int c    = cin_base + cc;
            float v = 0.f;
            if (co < COUT && c < cin)
                v = wsel[((size_t)co * ci_total + (w_cin_off + c)) * 9 + tap];
            lds_w[i] = v;
        }
        __syncthreads();

        #pragma unroll
        for (int cc = 0; cc < CHUNK; ++cc) {
            #pragma unroll
            for (int kh = 0; kh < 3; ++kh) {
                float iv[P + 2];
                const float* lrow = &lds_in[(cc * (ROWS + 2) + row + kh) * 66 + col0];
                #pragma unroll
                for (int u = 0; u < P + 2; ++u) iv[u] = lrow[u];
                #pragma unroll
                for (int j = 0; j < 4; ++j) {
                    const float* wrow = &lds_w[((wv * 4 + j) * CHUNK + cc) * 9 + kh * 3];
                    #pragma unroll
                    for (int kw = 0; kw < 3; ++kw) {
                        float wval = wrow[kw];
                        #pragma unroll
                        for (int p = 0; p < P; ++p)
                            acc[j][p] = fmaf(iv[p + kw], wval, acc[j][p]);
                    }
                }
            }
        }
    }

    if (MODE == 0) {
        #pragma unroll
        for (int j = 0; j < 4; ++j) {
            int co = co_grp * 16 + wv * 4 + j;
            if (co < COUT) {
                float* dst = convx + (img65 + co) * HW + px0;
                #pragma unroll
                for (int p = 0; p < P; ++p) dst[p] = acc[j][p];
            }
        }
    } else {
        const int chan_off = 64 * layer + (dir ? 32 : 0);
        const size_t imgOut = (size_t)(t * BATCH + b) * 256;
        const bool last_f = (dir == 0) && (step == T_STEPS - 1);
        #pragma unroll
        for (int j = 0; j < 4; ++j) {
            int co = co_grp * 16 + wv * 4 + j;
            if (co >= COUT) continue;
            if (co < G) {
                float* dst = out_t + (imgOut + chan_off + co) * HW + px0;
                float* dstl = last_f ? (lr_h + ((size_t)(layer * BATCH + b) * G + co) * HW + px0)
                                     : nullptr;
                #pragma unroll
                for (int p = 0; p < P; ++p) {
                    float v = tanhf(acc[j][p]);
                    dst[p] = v;
                    if (dstl) dstl[p] = v;
                }
            } else {
                float* dst = A_buf + ((size_t)(dir * BATCH + b) * 33 + (co - G)) * HW + px0;
                #pragma unroll
                for (int p = 0; p < P; ++p) dst[p] = tanhf(acc[j][p]);
            }
        }
    }
}

// c_next = sigmoid(A_gate) * A_cand ; store c, and lr_c / lr_g at last fwd step
__global__ __launch_bounds__(256) void cell_update(
    const float* __restrict__ A_buf, float* __restrict__ c_buf,
    float* __restrict__ lr_c, float* __restrict__ lr_g,
    int layer, int last)
{
    int idx = blockIdx.x * 256 + threadIdx.x;   // 2*4*32*4096
    int px  = idx & 4095;
    int k   = (idx >> 12) & 31;
    int b   = (idx >> 17) & 3;
    int dir = idx >> 19;
    size_t ab = (size_t)(dir * BATCH + b) * 33;
    float ga   = A_buf[(ab + 32) * HW + px];    // already tanh'd
    float g    = 1.f / (1.f + expf(-ga));
    float cand = A_buf[(ab + k) * HW + px];     // already tanh'd
    float c    = g * cand;
    c_buf[((size_t)(dir * BATCH + b) * G + k) * HW + px] = c;
    if (dir == 0 && last) {
        lr_c[((size_t)(layer * BATCH + b) * G + k) * HW + px] = c;
        if (k == 0) lr_g[(size_t)(layer * BATCH + b) * HW + px] = g;
    }
}

extern "C" void kernel_launch(void* const* d_in, const int* in_sizes, int n_in,
                              void* d_out, int out_size, void* d_ws, size_t ws_size,
                              hipStream_t stream)
{
    const float* x = (const float*)d_in[0];
    float* out = (float*)d_out;                       // (8,4,256,64,64)
    float* lrh = out + (size_t)33554432;              // (4,4,32,64,64)
    float* lrc = lrh + (size_t)2097152;               // (4,4,32,64,64)
    float* lrg = lrc + (size_t)2097152;               // (4,4,1,64,64)

    float* convx = (float*)d_ws;                              // 2*8*4*65*4096
    float* A_buf = convx + (size_t)2 * 8 * 4 * 65 * 4096;     // 2*4*33*4096
    float* c_buf = A_buf + (size_t)2 * 4 * 33 * 4096;         // 2*4*32*4096

    for (int l = 0; l < 4; ++l) {
        const float* wf = (const float*)d_in[1 + 4 * l];
        const float* bf = (const float*)d_in[2 + 4 * l];
        const float* wb = (const float*)d_in[3 + 4 * l];
        const float* bb = (const float*)d_in[4 + 4 * l];
        int cin = (l == 0) ? 32 : 64 * l;
        int ci_total = cin + 32;
        const float* in_base = (l == 0) ? x : out;
        int in_ctot = (l == 0) ? 32 : 256;

        // x-part conv for all (dir, t, b) of this layer
        conv_kernel<8, 0><<<dim3(8, 5, 64), 256, 0, stream>>>(
            in_base, in_ctot, cin, wf, wb, bf, bb, ci_total, 0,
            convx, nullptr, nullptr, nullptr, l, 0);

        hipMemsetAsync(c_buf, 0, (size_t)2 * 4 * 32 * 4096 * sizeof(float), stream);

        for (int s = 0; s < 8; ++s) {
            // recurrent conv (both directions in one launch)
            conv_kernel<4, 1><<<dim3(16, 5, 8), 256, 0, stream>>>(
                c_buf, 32, 32, wf, wb, nullptr, nullptr, ci_total, cin,
                convx, out, A_buf, lrh, l, s);
            cell_update<<<dim3(4096), 256, 0, stream>>>(
                A_buf, c_buf, lrc, lrg, l, s == 7);
        }
    }
}

// Round 2
// 2174.219 us; speedup vs baseline: 2.2787x; 2.2787x over previous
//
#include <hip/hip_runtime.h>
#include <math.h>

#define T_STEPS 8
#define BATCH 4
#define G 32
#define HW 4096
#define W64 64
#define COUT 65
#define CHUNK 8

typedef unsigned short u16;
typedef __attribute__((ext_vector_type(8))) short short8;
typedef __attribute__((ext_vector_type(4))) float f32x4;

__device__ __forceinline__ u16 f2bf(float f) {
    unsigned u = __builtin_bit_cast(unsigned, f);
    u += 0x7fffu + ((u >> 16) & 1u);
    return (u16)(u >> 16);
}

// ---------------------------------------------------------------------------
// Transpose fp32 [img][C][4096] channels [c0..c0+cin) -> bf16 XT[img][4096][cin]
// ---------------------------------------------------------------------------
__global__ __launch_bounds__(256) void transpose_bf16(
    const float* __restrict__ src, u16* __restrict__ XT,
    int src_ctot, int cin_pad)
{
    __shared__ float tile[32][257];
    const int img = blockIdx.z;
    const int px0 = blockIdx.x * 256;
    const int c0  = blockIdx.y * 32;
    const float* s = src + ((size_t)img * src_ctot + c0) * HW + px0;
    #pragma unroll
    for (int c = 0; c < 32; ++c)
        tile[c][threadIdx.x] = s[(size_t)c * HW + threadIdx.x];
    __syncthreads();
    const int c = threadIdx.x & 31, pb = threadIdx.x >> 5;
    u16* d = XT + ((size_t)img * HW + px0) * cin_pad + c0 + c;
    for (int p = pb; p < 256; p += 8)
        d[(size_t)p * cin_pad] = f2bf(tile[c][p]);
}

// ---------------------------------------------------------------------------
// Pack weights: fp32 w[co][ci_total][3][3] (x-part ci in [0,cin)) ->
// bf16 Wr[dir][tap][80][cin]  (rows >= 65 zeroed)
// ---------------------------------------------------------------------------
__global__ __launch_bounds__(256) void prep_w(
    const float* __restrict__ wf, const float* __restrict__ wb,
    u16* __restrict__ Wr, int cin, int ci_total)
{
    int idx = blockIdx.x * 256 + threadIdx.x;
    int total = 2 * 9 * 80 * cin;
    if (idx >= total) return;
    int ci = idx % cin;
    int rest = idx / cin;
    int co = rest % 80; rest /= 80;
    int tap = rest % 9;
    int dir = rest / 9;
    const float* w = dir ? wb : wf;
    float v = (co < COUT) ? w[((size_t)co * ci_total + ci) * 9 + tap] : 0.f;
    Wr[idx] = f2bf(v);
}

// ---------------------------------------------------------------------------
// MFMA implicit-GEMM x-conv: convx[dir][t][b][co][px] = bias + conv(x-part)
// Block: 256 thr = 4 waves, each wave owns one output row (64 px), all 80 co.
// 9 taps = 9 shifted GEMMs accumulated; K = cin chunks of 32.
// ---------------------------------------------------------------------------
__global__ __launch_bounds__(256) void convx_mfma(
    const u16* __restrict__ XT, const u16* __restrict__ Wr,
    const float* __restrict__ b_f, const float* __restrict__ b_b,
    float* __restrict__ convx, int cin)
{
    const int tid = threadIdx.x;
    const int l = tid & 63, wv = tid >> 6;
    const int g = l >> 4, ln16 = l & 15;
    const int z = blockIdx.z;
    const int dir = z >> 5, t = (z >> 2) & 7, b = z & 3;
    const int img = t * BATCH + b;
    const int orow = blockIdx.x * 4 + wv;

    const float* bias = dir ? b_b : b_f;
    f32x4 acc[5][4];
    #pragma unroll
    for (int mt = 0; mt < 5; ++mt) {
        #pragma unroll
        for (int r = 0; r < 4; ++r) {
            int co = mt * 16 + g * 4 + r;
            float bv = (co < COUT) ? bias[co] : 0.f;
            #pragma unroll
            for (int nt = 0; nt < 4; ++nt) acc[mt][nt][r] = bv;
        }
    }

    const u16* wdir = Wr + (size_t)dir * 9 * 80 * cin;
    const u16* xrow = XT + (size_t)img * HW * cin;

    for (int ch = 0; ch < cin; ch += 32) {
        #pragma unroll
        for (int ky = 0; ky < 3; ++ky) {
            int ry = orow + ky - 1;
            if ((unsigned)ry >= 64u) continue;     // zero-pad row: skip tap row
            #pragma unroll
            for (int kx = 0; kx < 3; ++kx) {
                const int tap = ky * 3 + kx;
                short8 af[5];
                const u16* wp = wdir + ((size_t)tap * 80 + ln16) * cin + ch + g * 8;
                #pragma unroll
                for (int mt = 0; mt < 5; ++mt)
                    af[mt] = *(const short8*)(wp + (size_t)mt * 16 * cin);
                #pragma unroll
                for (int nt = 0; nt < 4; ++nt) {
                    int col = nt * 16 + ln16 + kx - 1;
                    long px = (long)ry * 64 + col;
                    const u16* xp = xrow + px * (long)cin + ch + g * 8;
                    short8 bv = *(const short8*)xp;
                    if ((unsigned)col >= 64u) bv = (short8)0;   // zero-pad col
                    #pragma unroll
                    for (int mt = 0; mt < 5; ++mt)
                        acc[mt][nt] = __builtin_amdgcn_mfma_f32_16x16x32_bf16(
                            af[mt], bv, acc[mt][nt], 0, 0, 0);
                }
            }
        }
    }

    const size_t obase = ((size_t)(dir * T_STEPS + t) * BATCH + b) * COUT;
    #pragma unroll
    for (int mt = 0; mt < 5; ++mt) {
        #pragma unroll
        for (int r = 0; r < 4; ++r) {
            int co = mt * 16 + g * 4 + r;
            if (co >= COUT) continue;
            float* dst = convx + (obase + co) * HW + orow * 64;
            #pragma unroll
            for (int nt = 0; nt < 4; ++nt)
                dst[nt * 16 + ln16] = acc[mt][nt][r];
        }
    }
}

// ---------------------------------------------------------------------------
// Recurrent conv step (fp32 vector): acc = convx + conv(c); A = tanh(acc)
// co<32 -> h into out (+lr_h at last fwd step); co>=32 -> A_buf (cand+gate)
// ---------------------------------------------------------------------------
__global__ __launch_bounds__(256) void rec_conv(
    const float* __restrict__ c_in,
    const float* __restrict__ w_f, const float* __restrict__ w_b,
    int ci_total, int w_cin_off,
    const float* __restrict__ convx,
    float* __restrict__ out_t, float* __restrict__ A_buf,
    float* __restrict__ lr_h, int layer, int step)
{
    __shared__ float lds_in[CHUNK * 6 * 67];   // 67: 3 mod 32 -> <=2-way (free)
    __shared__ float lds_w[16 * CHUNK * 9];

    const int tid  = threadIdx.x;
    const int lane = tid & 63;
    const int wv   = tid >> 6;
    const int zz  = blockIdx.z;
    const int dir = zz >> 2, b = zz & 3;
    const int t   = dir ? (T_STEPS - 1 - step) : step;
    const int co_grp = blockIdx.y;
    const int row0   = blockIdx.x * 4;
    const int row = lane >> 4, col0 = (lane & 15) * 4;

    const float* wsel = dir ? w_b : w_f;
    const size_t in_chan0 = (size_t)(dir * BATCH + b) * 32;
    const size_t img65 = ((size_t)(dir * T_STEPS + t) * BATCH + b) * COUT;
    const int px0 = (row0 + row) * W64 + col0;

    float acc[4][4];
    #pragma unroll
    for (int j = 0; j < 4; ++j) {
        int co = co_grp * 16 + wv * 4 + j;
        if (co < COUT) {
            const float* srcp = convx + (img65 + co) * HW + px0;
            #pragma unroll
            for (int p = 0; p < 4; ++p) acc[j][p] = srcp[p];
        } else {
            #pragma unroll
            for (int p = 0; p < 4; ++p) acc[j][p] = 0.f;
        }
    }

    for (int ch = 0; ch < 4; ++ch) {
        const int cin_base = ch * CHUNK;
        __syncthreads();
        for (int i = tid; i < CHUNK * 6 * 66; i += 256) {
            int cc  = i / (6 * 66);
            int rem = i - cc * (6 * 66);
            int r   = rem / 66;
            int colp = rem - r * 66;
            int gr = row0 + r - 1;
            int gc = colp - 1;
            int c  = cin_base + cc;
            float v = 0.f;
            if ((unsigned)gr < 64u && (unsigned)gc < 64u)
                v = c_in[(in_chan0 + c) * HW + gr * W64 + gc];
            lds_in[(cc * 6 + r) * 67 + colp] = v;
        }
        for (int i = tid; i < 16 * CHUNK * 9; i += 256) {
            int col_ = i / (CHUNK * 9);
            int rem  = i - col_ * (CHUNK * 9);
            int cc   = rem / 9;
            int tap  = rem - cc * 9;
            int co   = co_grp * 16 + col_;
            int c    = cin_base + cc;
            float v = 0.f;
            if (co < COUT)
                v = wsel[((size_t)co * ci_total + (w_cin_off + c)) * 9 + tap];
            lds_w[i] = v;
        }
        __syncthreads();

        #pragma unroll
        for (int cc = 0; cc < CHUNK; ++cc) {
            #pragma unroll
            for (int kh = 0; kh < 3; ++kh) {
                float iv[6];
                const float* lrow = &lds_in[(cc * 6 + row + kh) * 67 + col0];
                #pragma unroll
                for (int u = 0; u < 6; ++u) iv[u] = lrow[u];
                #pragma unroll
                for (int j = 0; j < 4; ++j) {
                    const float* wrow = &lds_w[((wv * 4 + j) * CHUNK + cc) * 9 + kh * 3];
                    #pragma unroll
                    for (int kw = 0; kw < 3; ++kw) {
                        float wval = wrow[kw];
                        #pragma unroll
                        for (int p = 0; p < 4; ++p)
                            acc[j][p] = fmaf(iv[p + kw], wval, acc[j][p]);
                    }
                }
            }
        }
    }

    const int chan_off = 64 * layer + (dir ? 32 : 0);
    const size_t imgOut = (size_t)(t * BATCH + b) * 256;
    const bool last_f = (dir == 0) && (step == T_STEPS - 1);
    #pragma unroll
    for (int j = 0; j < 4; ++j) {
        int co = co_grp * 16 + wv * 4 + j;
        if (co >= COUT) continue;
        if (co < G) {
            float* dst = out_t + (imgOut + chan_off + co) * HW + px0;
            float* dstl = last_f ? (lr_h + ((size_t)(layer * BATCH + b) * G + co) * HW + px0)
                                 : nullptr;
            #pragma unroll
            for (int p = 0; p < 4; ++p) {
                float v = tanhf(acc[j][p]);
                dst[p] = v;
                if (dstl) dstl[p] = v;
            }
        } else {
            float* dst = A_buf + ((size_t)(dir * BATCH + b) * 33 + (co - G)) * HW + px0;
            #pragma unroll
            for (int p = 0; p < 4; ++p) dst[p] = tanhf(acc[j][p]);
        }
    }
}

__global__ __launch_bounds__(256) void cell_update(
    const float* __restrict__ A_buf, float* __restrict__ c_buf,
    float* __restrict__ lr_c, float* __restrict__ lr_g,
    int layer, int last)
{
    int idx = blockIdx.x * 256 + threadIdx.x;
    int px  = idx & 4095;
    int k   = (idx >> 12) & 31;
    int b   = (idx >> 17) & 3;
    int dir = idx >> 19;
    size_t ab = (size_t)(dir * BATCH + b) * 33;
    float ga   = A_buf[(ab + 32) * HW + px];
    float gg   = 1.f / (1.f + expf(-ga));
    float cand = A_buf[(ab + k) * HW + px];
    float c    = gg * cand;
    c_buf[((size_t)(dir * BATCH + b) * G + k) * HW + px] = c;
    if (dir == 0 && last) {
        lr_c[((size_t)(layer * BATCH + b) * G + k) * HW + px] = c;
        if (k == 0) lr_g[(size_t)(layer * BATCH + b) * HW + px] = gg;
    }
}

extern "C" void kernel_launch(void* const* d_in, const int* in_sizes, int n_in,
                              void* d_out, int out_size, void* d_ws, size_t ws_size,
                              hipStream_t stream)
{
    const float* x = (const float*)d_in[0];
    float* out = (float*)d_out;                       // (8,4,256,64,64)
    float* lrh = out + (size_t)33554432;
    float* lrc = lrh + (size_t)2097152;
    float* lrg = lrc + (size_t)2097152;

    float* convx = (float*)d_ws;                              // 17,039,360 f
    float* A_buf = convx + (size_t)17039360;                  // 1,081,344 f
    float* c_buf = A_buf + (size_t)1081344;                   // 1,048,576 f
    u16* XTg = (u16*)(c_buf + (size_t)1048576);
    u16* XT  = XTg + 2048;                                    // guard before
    u16* Wr  = XT + (size_t)32 * 4096 * 192 + 2048;           // guard after

    for (int l = 0; l < 4; ++l) {
        const float* wf = (const float*)d_in[1 + 4 * l];
        const float* bf = (const float*)d_in[2 + 4 * l];
        const float* wb = (const float*)d_in[3 + 4 * l];
        const float* bb = (const float*)d_in[4 + 4 * l];
        int cin = (l == 0) ? 32 : 64 * l;
        int ci_total = cin + 32;
        const float* src = (l == 0) ? x : out;
        int src_ctot = (l == 0) ? 32 : 256;

        transpose_bf16<<<dim3(16, cin / 32, 32), 256, 0, stream>>>(src, XT, src_ctot, cin);
        prep_w<<<dim3((2 * 9 * 80 * cin + 255) / 256), 256, 0, stream>>>(wf, wb, Wr, cin, ci_total);
        convx_mfma<<<dim3(16, 1, 64), 256, 0, stream>>>(XT, Wr, bf, bb, convx, cin);

        hipMemsetAsync(c_buf, 0, (size_t)2 * 4 * 32 * 4096 * sizeof(float), stream);

        for (int s = 0; s < 8; ++s) {
            rec_conv<<<dim3(16, 5, 8), 256, 0, stream>>>(
                c_buf, wf, wb, ci_total, cin, convx, out, A_buf, lrh, l, s);
            cell_update<<<dim3(4096), 256, 0, stream>>>(A_buf, c_buf, lrc, lrg, l, s == 7);
        }
    }
}

// Round 3
// 1280.162 us; speedup vs baseline: 3.8702x; 1.6984x over previous
//
#include <hip/hip_runtime.h>
#include <math.h>

#define T_STEPS 8
#define HW 4096
#define CO_S 68          // convx channel stride (co 0..67 stored)

typedef unsigned short u16;
typedef __attribute__((ext_vector_type(8))) short short8;
typedef __attribute__((ext_vector_type(4))) short short4v;
typedef __attribute__((ext_vector_type(4))) float f32x4;

__device__ __forceinline__ u16 f2bf(float f) {
    unsigned u = __builtin_bit_cast(unsigned, f);
    u += 0x7fffu + ((u >> 16) & 1u);
    return (u16)(u >> 16);
}
__device__ __forceinline__ float bf2f(u16 h) {
    unsigned u = ((unsigned)h) << 16;
    return __builtin_bit_cast(float, u);
}
__device__ __forceinline__ float sigm(float x) { return 1.f / (1.f + expf(-x)); }

// ---------------------------------------------------------------------------
// fp32 [img][src_ctot][64][64] (ch c0..c0+32) -> bf16 XT[img][66][66][cin] halo
// (border rows/cols pre-zeroed by memset)
// ---------------------------------------------------------------------------
__global__ __launch_bounds__(256) void transpose_halo(
    const float* __restrict__ src, u16* __restrict__ XT,
    int src_ctot, int cin)
{
    __shared__ float tile[32][257];
    const int img = blockIdx.z;
    const int px0 = blockIdx.x * 256;           // 4 rows of 64
    const int c0  = blockIdx.y * 32;
    const float* s = src + ((size_t)img * src_ctot + c0) * HW + px0;
    #pragma unroll
    for (int c = 0; c < 32; ++c)
        tile[c][threadIdx.x] = s[(size_t)c * HW + threadIdx.x];
    __syncthreads();
    const int c = threadIdx.x & 31, pb = threadIdx.x >> 5;
    const int r0 = px0 >> 6;
    for (int p = pb; p < 256; p += 8) {
        int row = r0 + (p >> 6), col = p & 63;
        XT[((size_t)img * 4356 + (row + 1) * 66 + col + 1) * cin + c0 + c] =
            f2bf(tile[c][p]);
    }
}

// ---------------------------------------------------------------------------
// Pack all weights (x-part and c-part): Wr[dir][tap][80][ci_total] bf16
// ---------------------------------------------------------------------------
__global__ __launch_bounds__(256) void prep_w(
    const float* __restrict__ wf, const float* __restrict__ wb,
    u16* __restrict__ Wr, int ci_total)
{
    int idx = blockIdx.x * 256 + threadIdx.x;
    int total = 2 * 9 * 80 * ci_total;
    if (idx >= total) return;
    int ci = idx % ci_total;
    int rest = idx / ci_total;
    int co = rest % 80; rest /= 80;
    int tap = rest % 9;
    int dir = rest / 9;
    const float* w = dir ? wb : wf;
    float v = (co < 65) ? w[((size_t)co * ci_total + ci) * 9 + tap] : 0.f;
    Wr[idx] = f2bf(v);
}

// ---------------------------------------------------------------------------
// Branchless MFMA x-conv. Wave = 1 output row x 80 co. Out: bf16 [img][px][68]
// ---------------------------------------------------------------------------
__global__ __launch_bounds__(256, 4) void convx_mfma(
    const u16* __restrict__ XT, const u16* __restrict__ Wr,
    const float* __restrict__ b_f, const float* __restrict__ b_b,
    u16* __restrict__ convx, int cin, int ci_total)
{
    const int tid = threadIdx.x;
    const int l = tid & 63, wv = tid >> 6;
    const int g = l >> 4, ln16 = l & 15;
    const int z = blockIdx.z;
    const int dir = z >> 5, t = (z >> 2) & 7, b = z & 3;
    const int orow = blockIdx.x * 4 + wv;

    const float* bias = dir ? b_b : b_f;
    f32x4 acc[5][4];
    #pragma unroll
    for (int mt = 0; mt < 5; ++mt)
        #pragma unroll
        for (int r = 0; r < 4; ++r) {
            int co = mt * 16 + g * 4 + r;
            float bv = (co < 65) ? bias[co] : 0.f;
            #pragma unroll
            for (int nt = 0; nt < 4; ++nt) acc[mt][nt][r] = bv;
        }

    const u16* wdir = Wr + (size_t)dir * 9 * 80 * ci_total + g * 8;
    const u16* xim  = XT + (size_t)(t * 4 + b) * 4356 * cin + g * 8;

    for (int ch = 0; ch < cin; ch += 32) {
        #pragma unroll
        for (int ky = 0; ky < 3; ++ky) {
            #pragma unroll
            for (int kx = 0; kx < 3; ++kx) {
                const int tap = ky * 3 + kx;
                const u16* xb = xim + ((size_t)((orow + ky) * 66 + ln16 + kx)) * cin + ch;
                short8 bv0 = *(const short8*)(xb);
                short8 bv1 = *(const short8*)(xb + (size_t)16 * cin);
                short8 bv2 = *(const short8*)(xb + (size_t)32 * cin);
                short8 bv3 = *(const short8*)(xb + (size_t)48 * cin);
                const u16* wb_ = wdir + ((size_t)tap * 80 + ln16) * ci_total + ch;
                #pragma unroll
                for (int mt = 0; mt < 5; ++mt) {
                    short8 af = *(const short8*)(wb_ + (size_t)mt * 16 * ci_total);
                    acc[mt][0] = __builtin_amdgcn_mfma_f32_16x16x32_bf16(af, bv0, acc[mt][0], 0, 0, 0);
                    acc[mt][1] = __builtin_amdgcn_mfma_f32_16x16x32_bf16(af, bv1, acc[mt][1], 0, 0, 0);
                    acc[mt][2] = __builtin_amdgcn_mfma_f32_16x16x32_bf16(af, bv2, acc[mt][2], 0, 0, 0);
                    acc[mt][3] = __builtin_amdgcn_mfma_f32_16x16x32_bf16(af, bv3, acc[mt][3], 0, 0, 0);
                }
            }
        }
    }

    u16* cb = convx + ((size_t)((dir * 8 + t) * 4 + b) * HW + orow * 64) * CO_S;
    #pragma unroll
    for (int mt = 0; mt < 5; ++mt) {
        if (mt < 4 || g == 0) {
            #pragma unroll
            for (int nt = 0; nt < 4; ++nt) {
                short4v pk;
                #pragma unroll
                for (int r = 0; r < 4; ++r) pk[r] = (short)f2bf(acc[mt][nt][r]);
                *(short4v*)(cb + (size_t)(nt * 16 + ln16) * CO_S + mt * 16 + g * 4) = pk;
            }
        }
    }
}

// ---------------------------------------------------------------------------
// Recurrent step, fully fused: acc = convx + conv(c_prev); A = tanh(acc);
// h -> out (+lr_h), gate = sigmoid(A[64]), c = gate*cand -> cT_out bf16 halo
// (+lr_c, lr_g at last fwd step). Wave = 1 row x 32 cols x 80 co.
// ---------------------------------------------------------------------------
__global__ __launch_bounds__(256) void rec_mfma(
    const u16* __restrict__ cT_in, u16* __restrict__ cT_out,
    const u16* __restrict__ Wr, const u16* __restrict__ convx,
    float* __restrict__ out_t,
    float* __restrict__ lrh, float* __restrict__ lrc, float* __restrict__ lrg,
    int cin, int ci_total, int layer, int step)
{
    const int tid = threadIdx.x;
    const int l = tid & 63, wv = tid >> 6;
    const int g = l >> 4, ln16 = l & 15;
    const int z = blockIdx.z;                  // dir*4 + b
    const int dir = z >> 2, b = z & 3;
    const int t = dir ? (7 - step) : step;
    const int row  = blockIdx.x * 2 + (wv >> 1);
    const int col0 = (wv & 1) * 32;

    // init acc from bf16 convx [img][px][68]
    f32x4 acc[5][2];
    const u16* cxb = convx + ((size_t)((dir * 8 + t) * 4 + b) * HW + row * 64 + col0) * CO_S;
    #pragma unroll
    for (int mt = 0; mt < 5; ++mt)
        #pragma unroll
        for (int nt = 0; nt < 2; ++nt) {
            if (mt < 4 || g == 0) {
                short4v pk = *(const short4v*)(cxb + (size_t)(nt * 16 + ln16) * CO_S + mt * 16 + g * 4);
                #pragma unroll
                for (int r = 0; r < 4; ++r) acc[mt][nt][r] = bf2f((u16)pk[r]);
            } else {
                #pragma unroll
                for (int r = 0; r < 4; ++r) acc[mt][nt][r] = 0.f;
            }
        }

    const u16* wdir = Wr + (size_t)dir * 9 * 80 * ci_total + cin + g * 8;
    const u16* cim  = cT_in + (size_t)z * 4356 * 32 + g * 8;

    #pragma unroll
    for (int ky = 0; ky < 3; ++ky) {
        #pragma unroll
        for (int kx = 0; kx < 3; ++kx) {
            const int tap = ky * 3 + kx;
            const u16* xb = cim + (size_t)((row + ky) * 66 + col0 + ln16 + kx) * 32;
            short8 bv0 = *(const short8*)(xb);
            short8 bv1 = *(const short8*)(xb + 16 * 32);
            const u16* wb_ = wdir + ((size_t)tap * 80 + ln16) * ci_total;
            #pragma unroll
            for (int mt = 0; mt < 5; ++mt) {
                short8 af = *(const short8*)(wb_ + (size_t)mt * 16 * ci_total);
                acc[mt][0] = __builtin_amdgcn_mfma_f32_16x16x32_bf16(af, bv0, acc[mt][0], 0, 0, 0);
                acc[mt][1] = __builtin_amdgcn_mfma_f32_16x16x32_bf16(af, bv1, acc[mt][1], 0, 0, 0);
            }
        }
    }

    const bool last_f = (dir == 0) && (step == 7);
    float val[2], gv[2];
    #pragma unroll
    for (int nt = 0; nt < 2; ++nt) {
        val[nt] = sigm(tanhf(acc[4][nt][0]));
        gv[nt]  = __shfl(val[nt], ln16);       // gate lives in g==0 lanes
    }

    const size_t obase = (size_t)(t * 4 + b) * 256 + 64 * layer + dir * 32;
    #pragma unroll
    for (int mt = 0; mt < 2; ++mt)
        #pragma unroll
        for (int nt = 0; nt < 2; ++nt)
            #pragma unroll
            for (int r = 0; r < 4; ++r) {
                int co = mt * 16 + g * 4 + r;
                int px = row * 64 + col0 + nt * 16 + ln16;
                float v = tanhf(acc[mt][nt][r]);
                out_t[(obase + co) * HW + px] = v;
                if (last_f) lrh[((size_t)(layer * 4 + b) * 32 + co) * HW + px] = v;
            }
    #pragma unroll
    for (int mt = 2; mt < 4; ++mt)
        #pragma unroll
        for (int nt = 0; nt < 2; ++nt) {
            short4v pk;
            #pragma unroll
            for (int r = 0; r < 4; ++r) {
                int k = (mt - 2) * 16 + g * 4 + r;
                float c = gv[nt] * tanhf(acc[mt][nt][r]);
                pk[r] = (short)f2bf(c);
                if (last_f)
                    lrc[((size_t)(layer * 4 + b) * 32 + k) * HW + row * 64 + col0 + nt * 16 + ln16] = c;
            }
            int colh = col0 + nt * 16 + ln16 + 1;
            *(short4v*)(cT_out + ((size_t)z * 4356 + (row + 1) * 66 + colh) * 32 + (mt - 2) * 16 + g * 4) = pk;
        }
    if (last_f && g == 0) {
        #pragma unroll
        for (int nt = 0; nt < 2; ++nt)
            lrg[(size_t)(layer * 4 + b) * HW + row * 64 + col0 + nt * 16 + ln16] = val[nt];
    }
}

extern "C" void kernel_launch(void* const* d_in, const int* in_sizes, int n_in,
                              void* d_out, int out_size, void* d_ws, size_t ws_size,
                              hipStream_t stream)
{
    const float* x = (const float*)d_in[0];
    float* out = (float*)d_out;                       // (8,4,256,64,64)
    float* lrh = out + (size_t)33554432;
    float* lrc = lrh + (size_t)2097152;
    float* lrg = lrc + (size_t)2097152;

    char* ws = (char*)d_ws;
    u16* convx = (u16*)ws;                            // 64*4096*68*2 = 35,651,584 B
    size_t off = 35651584 + 4096;                     // guard (rec garbage-row reads)
    u16* cT_a = (u16*)(ws + off); off += 2230272;     // 8*4356*32*2
    u16* cT_b = (u16*)(ws + off); off += 2230272;
    u16* XT   = (u16*)(ws + off); off += 53526528;    // 32*4356*192*2 (max)
    u16* Wr   = (u16*)(ws + off);                     // 2*9*80*224*2 = 645,120 B

    for (int l = 0; l < 4; ++l) {
        const float* wf = (const float*)d_in[1 + 4 * l];
        const float* bf = (const float*)d_in[2 + 4 * l];
        const float* wb = (const float*)d_in[3 + 4 * l];
        const float* bb = (const float*)d_in[4 + 4 * l];
        int cin = (l == 0) ? 32 : 64 * l;
        int ci_total = cin + 32;
        const float* src = (l == 0) ? x : out;
        int src_ctot = (l == 0) ? 32 : 256;

        hipMemsetAsync(XT, 0, (size_t)32 * 4356 * cin * 2, stream);
        transpose_halo<<<dim3(16, cin / 32, 32), 256, 0, stream>>>(src, XT, src_ctot, cin);
        prep_w<<<dim3((2 * 9 * 80 * ci_total + 255) / 256), 256, 0, stream>>>(wf, wb, Wr, ci_total);
        convx_mfma<<<dim3(16, 1, 64), 256, 0, stream>>>(XT, Wr, bf, bb, convx, cin, ci_total);

        hipMemsetAsync(cT_a, 0, 2230272, stream);
        hipMemsetAsync(cT_b, 0, 2230272, stream);

        for (int s = 0; s < 8; ++s) {
            const u16* cin_p = (s & 1) ? cT_b : cT_a;
            u16* cout_p      = (s & 1) ? cT_a : cT_b;
            rec_mfma<<<dim3(32, 1, 8), 256, 0, stream>>>(
                cin_p, cout_p, Wr, convx, out, lrh, lrc, lrg, cin, ci_total, l, s);
        }
    }
}

// Round 4
// 861.418 us; speedup vs baseline: 5.7515x; 1.4861x over previous
//
#include <hip/hip_runtime.h>
#include <math.h>

#define T_STEPS 8
#define HW 4096

typedef unsigned short u16;
typedef __attribute__((ext_vector_type(8))) short short8;
typedef __attribute__((ext_vector_type(4))) short short4v;
typedef __attribute__((ext_vector_type(4))) float f32x4;

__device__ __forceinline__ u16 f2bf(float f) {
    unsigned u = __builtin_bit_cast(unsigned, f);
    u += 0x7fffu + ((u >> 16) & 1u);
    return (u16)(u >> 16);
}
__device__ __forceinline__ float bf2f(u16 h) {
    unsigned u = ((unsigned)h) << 16;
    return __builtin_bit_cast(float, u);
}
__device__ __forceinline__ float sigm(float x) { return 1.f / (1.f + expf(-x)); }

// convx fragment layout, per (img,row): 16 full frags (nt*4+mt)*256 u16
// (lane-major, 4 co per lane) + mt=4 quarter frags at 4096 + nt*64 + ln16*4.
// Per (img,row) = 4352 u16. img index = dir*32 + t*4 + b.
#define FR_ROW 4352

// ---------------------------------------------------------------------------
// fp32 [img][src_ctot][64][64] (ch c0..c0+32) -> bf16 XT[img][66][66][cin] halo
// (border pre-zeroed by memset)
// ---------------------------------------------------------------------------
__global__ __launch_bounds__(256) void transpose_halo(
    const float* __restrict__ src, u16* __restrict__ XT,
    int src_ctot, int cin)
{
    __shared__ float tile[32][257];
    const int img = blockIdx.z;
    const int px0 = blockIdx.x * 256;           // 4 rows of 64
    const int c0  = blockIdx.y * 32;
    const float* s = src + ((size_t)img * src_ctot + c0) * HW + px0;
    #pragma unroll
    for (int c = 0; c < 32; ++c)
        tile[c][threadIdx.x] = s[(size_t)c * HW + threadIdx.x];
    __syncthreads();
    const int c = threadIdx.x & 31, pb = threadIdx.x >> 5;
    const int r0 = px0 >> 6;
    for (int p = pb; p < 256; p += 8) {
        int row = r0 + (p >> 6), col = p & 63;
        XT[((size_t)img * 4356 + (row + 1) * 66 + col + 1) * cin + c0 + c] =
            f2bf(tile[c][p]);
    }
}

// ---------------------------------------------------------------------------
// Pack all weights: Wr[dir][tap][80][ci_total] bf16 (rows >= 65 zeroed)
// ---------------------------------------------------------------------------
__global__ __launch_bounds__(256) void prep_w(
    const float* __restrict__ wf, const float* __restrict__ wb,
    u16* __restrict__ Wr, int ci_total)
{
    int idx = blockIdx.x * 256 + threadIdx.x;
    int total = 2 * 9 * 80 * ci_total;
    if (idx >= total) return;
    int ci = idx % ci_total;
    int rest = idx / ci_total;
    int co = rest % 80; rest /= 80;
    int tap = rest % 9;
    int dir = rest / 9;
    const float* w = dir ? wb : wf;
    float v = (co < 65) ? w[((size_t)co * ci_total + ci) * 9 + tap] : 0.f;
    Wr[idx] = f2bf(v);
}

// ---------------------------------------------------------------------------
// MFMA x-conv, LDS-staged. Block = 4 waves = 4 output rows; per ch-chunk
// stage [6 rows][66 px][32 ch] bf16 (25.3 KB), reuse across 9 taps x 4 waves.
// Output: convx fragments (see FR_ROW).
// ---------------------------------------------------------------------------
__global__ __launch_bounds__(256, 4) void convx_mfma(
    const u16* __restrict__ XT, const u16* __restrict__ Wr,
    const float* __restrict__ b_f, const float* __restrict__ b_b,
    u16* __restrict__ convx, int cin, int ci_total)
{
    __shared__ u16 xs[6 * 66 * 32];       // 25,344 B
    const int tid = threadIdx.x;
    const int l = tid & 63, wv = tid >> 6;
    const int g = l >> 4, ln16 = l & 15;
    const int z = blockIdx.z;             // dir*32 + t*4 + b == output img idx
    const int dir = z >> 5;
    const int img = z & 31;               // t*4+b (XT img)
    const int r0  = blockIdx.x * 4;
    const int orow = r0 + wv;

    const float* bias = dir ? b_b : b_f;
    f32x4 acc[5][4];
    #pragma unroll
    for (int mt = 0; mt < 5; ++mt)
        #pragma unroll
        for (int r = 0; r < 4; ++r) {
            int co = mt * 16 + g * 4 + r;
            float bv = (co < 65) ? bias[co] : 0.f;
            #pragma unroll
            for (int nt = 0; nt < 4; ++nt) acc[mt][nt][r] = bv;
        }

    const u16* wdir = Wr + (size_t)dir * 9 * 80 * ci_total + g * 8;
    const u16* xim  = XT + (size_t)img * 4356 * cin;

    for (int ch = 0; ch < cin; ch += 32) {
        __syncthreads();
        // stage: XT halo-rows r0..r0+5, all 66 px, 32 ch -> 1584 x 16B
        #pragma unroll
        for (int k = 0; k < 7; ++k) {
            int idx = k * 256 + tid;
            if (idx < 1584) {
                int seg = idx & 3;
                int pr  = idx >> 2;       // 0..395 = row*66+px
                short8 v = *(const short8*)(xim + ((size_t)(r0 * 66 + pr)) * cin + ch + seg * 8);
                *(short8*)(xs + (size_t)idx * 8) = v;
            }
        }
        __syncthreads();

        #pragma unroll
        for (int ky = 0; ky < 3; ++ky) {
            #pragma unroll
            for (int kx = 0; kx < 3; ++kx) {
                const int tap = ky * 3 + kx;
                const u16* xb = xs + ((size_t)((wv + ky) * 66 + ln16 + kx)) * 32 + g * 8;
                short8 bv0 = *(const short8*)(xb);
                short8 bv1 = *(const short8*)(xb + 16 * 32);
                short8 bv2 = *(const short8*)(xb + 32 * 32);
                short8 bv3 = *(const short8*)(xb + 48 * 32);
                const u16* wb_ = wdir + ((size_t)tap * 80 + ln16) * ci_total + ch;
                #pragma unroll
                for (int mt = 0; mt < 5; ++mt) {
                    short8 af = *(const short8*)(wb_ + (size_t)mt * 16 * ci_total);
                    acc[mt][0] = __builtin_amdgcn_mfma_f32_16x16x32_bf16(af, bv0, acc[mt][0], 0, 0, 0);
                    acc[mt][1] = __builtin_amdgcn_mfma_f32_16x16x32_bf16(af, bv1, acc[mt][1], 0, 0, 0);
                    acc[mt][2] = __builtin_amdgcn_mfma_f32_16x16x32_bf16(af, bv2, acc[mt][2], 0, 0, 0);
                    acc[mt][3] = __builtin_amdgcn_mfma_f32_16x16x32_bf16(af, bv3, acc[mt][3], 0, 0, 0);
                }
            }
        }
    }

    // fragment-layout store: wave writes 512B contiguous per frag
    u16* cb = convx + ((size_t)z * 64 + orow) * FR_ROW;
    #pragma unroll
    for (int mt = 0; mt < 4; ++mt)
        #pragma unroll
        for (int nt = 0; nt < 4; ++nt) {
            short4v pk;
            #pragma unroll
            for (int r = 0; r < 4; ++r) pk[r] = (short)f2bf(acc[mt][nt][r]);
            *(short4v*)(cb + (size_t)(nt * 4 + mt) * 256 + l * 4) = pk;
        }
    if (g == 0) {
        #pragma unroll
        for (int nt = 0; nt < 4; ++nt) {
            short4v pk;
            #pragma unroll
            for (int r = 0; r < 4; ++r) pk[r] = (short)f2bf(acc[4][nt][r]);
            *(short4v*)(cb + 4096 + nt * 64 + ln16 * 4) = pk;
        }
    }
}

// ---------------------------------------------------------------------------
// Recurrent step, fused: acc = convx + conv(c_prev); A = tanh(acc);
// h -> out (+lr_h), gate = sigmoid(A[64]), c = gate*cand -> cT_out bf16 halo
// Wave = 1 row x 32 cols x 80 co.
// ---------------------------------------------------------------------------
__global__ __launch_bounds__(256) void rec_mfma(
    const u16* __restrict__ cT_in, u16* __restrict__ cT_out,
    const u16* __restrict__ Wr, const u16* __restrict__ convx,
    float* __restrict__ out_t,
    float* __restrict__ lrh, float* __restrict__ lrc, float* __restrict__ lrg,
    int cin, int ci_total, int layer, int step)
{
    const int tid = threadIdx.x;
    const int l = tid & 63, wv = tid >> 6;
    const int g = l >> 4, ln16 = l & 15;
    const int z = blockIdx.z;                  // dir*4 + b
    const int dir = z >> 2, b = z & 3;
    const int t = dir ? (7 - step) : step;
    const int row  = blockIdx.x * 2 + (wv >> 1);
    const int nb   = (wv & 1) * 2;             // nt base (col0 = nb*16)
    const int col0 = nb * 16;

    // init acc from convx fragments (coalesced: 8B/lane, 512B/wave)
    const int zimg = dir * 32 + t * 4 + b;
    const u16* cxb = convx + ((size_t)zimg * 64 + row) * FR_ROW;
    f32x4 acc[5][2];
    #pragma unroll
    for (int mt = 0; mt < 4; ++mt)
        #pragma unroll
        for (int nt = 0; nt < 2; ++nt) {
            short4v pk = *(const short4v*)(cxb + (size_t)((nb + nt) * 4 + mt) * 256 + l * 4);
            #pragma unroll
            for (int r = 0; r < 4; ++r) acc[mt][nt][r] = bf2f((u16)pk[r]);
        }
    #pragma unroll
    for (int nt = 0; nt < 2; ++nt) {
        if (g == 0) {
            short4v pk = *(const short4v*)(cxb + 4096 + (nb + nt) * 64 + ln16 * 4);
            #pragma unroll
            for (int r = 0; r < 4; ++r) acc[4][nt][r] = bf2f((u16)pk[r]);
        } else {
            #pragma unroll
            for (int r = 0; r < 4; ++r) acc[4][nt][r] = 0.f;
        }
    }

    const u16* wdir = Wr + (size_t)dir * 9 * 80 * ci_total + cin + g * 8;
    const u16* cim  = cT_in + (size_t)z * 4356 * 32 + g * 8;

    #pragma unroll
    for (int ky = 0; ky < 3; ++ky) {
        #pragma unroll
        for (int kx = 0; kx < 3; ++kx) {
            const int tap = ky * 3 + kx;
            const u16* xb = cim + (size_t)((row + ky) * 66 + col0 + ln16 + kx) * 32;
            short8 bv0 = *(const short8*)(xb);
            short8 bv1 = *(const short8*)(xb + 16 * 32);
            const u16* wb_ = wdir + ((size_t)tap * 80 + ln16) * ci_total;
            #pragma unroll
            for (int mt = 0; mt < 5; ++mt) {
                short8 af = *(const short8*)(wb_ + (size_t)mt * 16 * ci_total);
                acc[mt][0] = __builtin_amdgcn_mfma_f32_16x16x32_bf16(af, bv0, acc[mt][0], 0, 0, 0);
                acc[mt][1] = __builtin_amdgcn_mfma_f32_16x16x32_bf16(af, bv1, acc[mt][1], 0, 0, 0);
            }
        }
    }

    const bool last_f = (dir == 0) && (step == 7);
    float val[2], gv[2];
    #pragma unroll
    for (int nt = 0; nt < 2; ++nt) {
        val[nt] = sigm(tanhf(acc[4][nt][0]));
        gv[nt]  = __shfl(val[nt], ln16);       // broadcast from g==0 lanes
    }

    const size_t obase = (size_t)(t * 4 + b) * 256 + 64 * layer + dir * 32;
    #pragma unroll
    for (int mt = 0; mt < 2; ++mt)
        #pragma unroll
        for (int nt = 0; nt < 2; ++nt)
            #pragma unroll
            for (int r = 0; r < 4; ++r) {
                int co = mt * 16 + g * 4 + r;
                int px = row * 64 + col0 + nt * 16 + ln16;
                float v = tanhf(acc[mt][nt][r]);
                out_t[(obase + co) * HW + px] = v;
                if (last_f) lrh[((size_t)(layer * 4 + b) * 32 + co) * HW + px] = v;
            }
    #pragma unroll
    for (int mt = 2; mt < 4; ++mt)
        #pragma unroll
        for (int nt = 0; nt < 2; ++nt) {
            short4v pk;
            #pragma unroll
            for (int r = 0; r < 4; ++r) {
                int k = (mt - 2) * 16 + g * 4 + r;
                float c = gv[nt] * tanhf(acc[mt][nt][r]);
                pk[r] = (short)f2bf(c);
                if (last_f)
                    lrc[((size_t)(layer * 4 + b) * 32 + k) * HW + row * 64 + col0 + nt * 16 + ln16] = c;
            }
            int colh = col0 + nt * 16 + ln16 + 1;
            *(short4v*)(cT_out + ((size_t)z * 4356 + (row + 1) * 66 + colh) * 32 + (mt - 2) * 16 + g * 4) = pk;
        }
    if (last_f && g == 0) {
        #pragma unroll
        for (int nt = 0; nt < 2; ++nt)
            lrg[(size_t)(layer * 4 + b) * HW + row * 64 + col0 + nt * 16 + ln16] = val[nt];
    }
}

extern "C" void kernel_launch(void* const* d_in, const int* in_sizes, int n_in,
                              void* d_out, int out_size, void* d_ws, size_t ws_size,
                              hipStream_t stream)
{
    const float* x = (const float*)d_in[0];
    float* out = (float*)d_out;                       // (8,4,256,64,64)
    float* lrh = out + (size_t)33554432;
    float* lrc = lrh + (size_t)2097152;
    float* lrg = lrc + (size_t)2097152;

    char* ws = (char*)d_ws;
    u16* convx = (u16*)ws;                            // 64*64*4352*2 = 35,651,584 B
    size_t off = 35651584 + 4096;
    u16* cT_a = (u16*)(ws + off); off += 2230272;     // 8*4356*32*2
    u16* cT_b = (u16*)(ws + off); off += 2230272;
    u16* XT   = (u16*)(ws + off); off += 53526528;    // 32*4356*192*2 (max)
    u16* Wr   = (u16*)(ws + off);                     // 2*9*80*224*2 = 645,120 B

    for (int l = 0; l < 4; ++l) {
        const float* wf = (const float*)d_in[1 + 4 * l];
        const float* bf = (const float*)d_in[2 + 4 * l];
        const float* wb = (const float*)d_in[3 + 4 * l];
        const float* bb = (const float*)d_in[4 + 4 * l];
        int cin = (l == 0) ? 32 : 64 * l;
        int ci_total = cin + 32;
        const float* src = (l == 0) ? x : out;
        int src_ctot = (l == 0) ? 32 : 256;

        hipMemsetAsync(XT, 0, (size_t)32 * 4356 * cin * 2, stream);
        transpose_halo<<<dim3(16, cin / 32, 32), 256, 0, stream>>>(src, XT, src_ctot, cin);
        prep_w<<<dim3((2 * 9 * 80 * ci_total + 255) / 256), 256, 0, stream>>>(wf, wb, Wr, ci_total);
        convx_mfma<<<dim3(16, 1, 64), 256, 0, stream>>>(XT, Wr, bf, bb, convx, cin, ci_total);

        hipMemsetAsync(cT_a, 0, 2230272, stream);
        hipMemsetAsync(cT_b, 0, 2230272, stream);

        for (int s = 0; s < 8; ++s) {
            const u16* cin_p = (s & 1) ? cT_b : cT_a;
            u16* cout_p      = (s & 1) ? cT_a : cT_b;
            rec_mfma<<<dim3(32, 1, 8), 256, 0, stream>>>(
                cin_p, cout_p, Wr, convx, out, lrh, lrc, lrg, cin, ci_total, l, s);
        }
    }
}